// Round 6
// baseline (323.457 us; speedup 1.0000x reference)
//
#include <hip/hip_runtime.h>

// Problem constants (from reference): N=512, OBS=32, H=128, M=128, L=3
#define NA 512
#define NOBS 32
#define NH 128

typedef const float* fp32p;
typedef __attribute__((ext_vector_type(8))) short bf16x8;
typedef __attribute__((ext_vector_type(4))) float f32x4;

// fp32 -> bf16 (RNE) bit pattern
__device__ __forceinline__ short f2bf(float f) {
    union { float f; unsigned u; } v; v.f = f;
    unsigned r = v.u + 0x7fffu + ((v.u >> 16) & 1u);
    return (short)(r >> 16);
}

__device__ __forceinline__ bf16x8 wfrag_f4(const float* p) {  // 16B-aligned
    float4 u = *(const float4*)p;
    float4 v = *(const float4*)(p + 4);
    bf16x8 f;
    f[0] = f2bf(u.x); f[1] = f2bf(u.y); f[2] = f2bf(u.z); f[3] = f2bf(u.w);
    f[4] = f2bf(v.x); f[5] = f2bf(v.y); f[6] = f2bf(v.z); f[7] = f2bf(v.w);
    return f;
}
__device__ __forceinline__ bf16x8 wfrag_s(const float* p) {   // unaligned ok
    bf16x8 f;
    #pragma unroll
    for (int j = 0; j < 8; ++j) f[j] = f2bf(p[j]);
    return f;
}

#define HSTR 136   // LDS row stride (shorts) for 128-wide bf16 tiles
#define XSTR 40    // for 32-wide obs tile

// ------------------------------------------------ encoder + ab(layer0) -----
// grid 32 x 512; all weight fragments loaded before the first barrier so the
// 5-phase MFMA chain overlaps its global loads.
__global__ __launch_bounds__(512) void enc_ab_kernel(
    fp32p obs, fp32p W1, fp32p b1, fp32p W2, fp32p b2, fp32p W3, fp32p b3,
    fp32p msgW1, float* __restrict__ z, float* __restrict__ A, float* __restrict__ B) {
    const int a0 = blockIdx.x * 16;
    const int t = threadIdx.x;
    const int lane = t & 63, w = t >> 6, q = lane >> 4, c = lane & 15;
    const int ncol = w * 16 + c;

    __shared__ short xs[16 * XSTR];
    __shared__ short h1s[16 * HSTR];
    __shared__ short h2s[16 * HSTR];

    // hoisted weight fragments (independent of LDS)
    bf16x8 wf = wfrag_f4(W1 + (size_t)ncol * NOBS + q * 8);
    bf16x8 w2f[4], w3f[4], wif[4], wjf[4];
    #pragma unroll
    for (int kb = 0; kb < 4; ++kb) {
        w2f[kb] = wfrag_f4(W2 + (size_t)ncol * NH + kb * 32 + q * 8);
        w3f[kb] = wfrag_f4(W3 + (size_t)ncol * NH + kb * 32 + q * 8);
        const float* pr = msgW1 + (size_t)ncol * 257 + kb * 32 + q * 8;
        wif[kb] = wfrag_s(pr);
        wjf[kb] = wfrag_s(pr + NH);
    }
    const float bias1 = b1[ncol], bias2 = b2[ncol], bias3 = b3[ncol];

    {   // 512 threads, 512 elements
        const int r = t >> 5, k = t & 31;
        xs[r * XSTR + k] = f2bf(obs[(size_t)(a0 + r) * NOBS + k]);
    }
    __syncthreads();
    // L1 (K=32)
    {
        f32x4 acc = {0.f, 0.f, 0.f, 0.f};
        bf16x8 a = *(const bf16x8*)&xs[c * XSTR + q * 8];
        acc = __builtin_amdgcn_mfma_f32_16x16x32_bf16(a, wf, acc, 0, 0, 0);
        #pragma unroll
        for (int r = 0; r < 4; ++r)
            h1s[(q * 4 + r) * HSTR + ncol] = f2bf(fmaxf(acc[r] + bias1, 0.f));
    }
    __syncthreads();
    // L2 (K=128)
    {
        f32x4 acc = {0.f, 0.f, 0.f, 0.f};
        #pragma unroll
        for (int kb = 0; kb < 4; ++kb) {
            bf16x8 a = *(const bf16x8*)&h1s[c * HSTR + kb * 32 + q * 8];
            acc = __builtin_amdgcn_mfma_f32_16x16x32_bf16(a, w2f[kb], acc, 0, 0, 0);
        }
        #pragma unroll
        for (int r = 0; r < 4; ++r)
            h2s[(q * 4 + r) * HSTR + ncol] = f2bf(fmaxf(acc[r] + bias2, 0.f));
    }
    __syncthreads();
    // L3 (K=128, no relu) -> z fp32 + bf16 back into h1s
    {
        f32x4 acc = {0.f, 0.f, 0.f, 0.f};
        #pragma unroll
        for (int kb = 0; kb < 4; ++kb) {
            bf16x8 a = *(const bf16x8*)&h2s[c * HSTR + kb * 32 + q * 8];
            acc = __builtin_amdgcn_mfma_f32_16x16x32_bf16(a, w3f[kb], acc, 0, 0, 0);
        }
        #pragma unroll
        for (int r = 0; r < 4; ++r) {
            const int row = q * 4 + r;
            const float v = acc[r] + bias3;
            z[(size_t)(a0 + row) * NH + ncol] = v;
            h1s[row * HSTR + ncol] = f2bf(v);
        }
    }
    __syncthreads();
    // ab for msg layer 0
    {
        f32x4 accA = {0.f, 0.f, 0.f, 0.f};
        f32x4 accB = {0.f, 0.f, 0.f, 0.f};
        #pragma unroll
        for (int kb = 0; kb < 4; ++kb) {
            bf16x8 a = *(const bf16x8*)&h1s[c * HSTR + kb * 32 + q * 8];
            accA = __builtin_amdgcn_mfma_f32_16x16x32_bf16(a, wif[kb], accA, 0, 0, 0);
            accB = __builtin_amdgcn_mfma_f32_16x16x32_bf16(a, wjf[kb], accB, 0, 0, 0);
        }
        #pragma unroll
        for (int r = 0; r < 4; ++r) {
            const int row = q * 4 + r;
            A[(size_t)(a0 + row) * NH + ncol] = accA[r];
            B[(size_t)(a0 + row) * NH + ncol] = accB[r];
        }
    }
}

// -------------------------------------- fused message + update + next-ab ----
// One block per agent i; 8 waves. Msg GEMMs: wave (g=w>>2, cg=w&3) owns rows
// [32g,32g+32) x cols [32cg,32cg+32) (2 n-tiles) -> each A-fragment b128 is
// reused for 2 MFMAs, halving LDS A-traffic vs round 5. Tail: coalesced GEMV
// (wave = one output row at a time, lanes split k, shuffle-reduce).
__global__ __launch_bounds__(512, 4) void msg_upd_kernel(
    const float* __restrict__ A, const float* __restrict__ B,
    fp32p pos, const float* __restrict__ zin,
    fp32p W1l, fp32p b1, fp32p W2, fp32p b2, fp32p W3, fp32p b3,
    fp32p uW1, fp32p ub1, fp32p uW2, fp32p ub2, fp32p uW3, fp32p ub3,
    fp32p msgW1n, int do_ab,
    float* __restrict__ zout, float* __restrict__ An, float* __restrict__ Bn) {
    const int i = blockIdx.x;
    const int t = threadIdx.x;
    const int lane = t & 63;
    const int w = t >> 6;
    const int q = lane >> 4;
    const int c = lane & 15;
    const int g  = w >> 2;        // row-group 0/1 (32 rows)
    const int cg = w & 3;         // col-group (32 cols = 2 n-tiles)
    const int n0 = cg * 32 + c;   // n-tile 0 column
    const int n1 = n0 + 16;       // n-tile 1 column

    __shared__ short h1s[64 * HSTR];   // 17408 B
    __shared__ short h2s[64 * HSTR];   // 17408 B
    __shared__ float distrow[NA];
    __shared__ float amrow[NH];        // A_i + b1 folded
    __shared__ float wdsr[NH];
    __shared__ float msum_s[NH];
    __shared__ float xs2[2 * NH];      // [z_i | msum_i]
    __shared__ float hx[NH], hy[NH], hz[NH];

    if (t < NH) {
        amrow[t] = A[i * NH + t] + b1[t];
        wdsr[t]  = W1l[t * 257 + 256];
        msum_s[t] = 0.0f;
        xs2[t] = zin[(size_t)i * NH + t];
    }
    {
        const float2 pi = *(const float2*)&pos[2 * i];
        const float2 pj = *(const float2*)&pos[2 * t];
        const float dx = pi.x - pj.x, dy = pi.y - pj.y;
        const float s = dx * dx + dy * dy;
        distrow[t] = (t == i) ? 0.0f : sqrtf(s);
    }

    // register-resident weight fragments: 2 n-tiles x 4 k-blocks, both GEMMs
    bf16x8 w2f[2][4], w3f[2][4];
    #pragma unroll
    for (int nt = 0; nt < 2; ++nt) {
        const float* w2r = W2 + (size_t)(n0 + nt * 16) * NH + q * 8;
        const float* w3r = W3 + (size_t)(n0 + nt * 16) * NH + q * 8;
        #pragma unroll
        for (int kb = 0; kb < 4; ++kb) {
            w2f[nt][kb] = wfrag_f4(w2r + kb * 32);
            w3f[nt][kb] = wfrag_f4(w3r + kb * 32);
        }
    }
    const float b2n0 = b2[n0], b2n1 = b2[n1];
    const float b3n0 = b3[n0], b3n1 = b3[n1];

    const int m2 = lane * 2;
    float psum0 = 0.0f, psum1 = 0.0f;

    for (int c8 = 0; c8 < 8; ++c8) {
        const int j0 = c8 * 64;
        __syncthreads();

        // ---- build h1 chunk (64 x 128) as bf16 ----
        {
            const float am0 = amrow[m2],     am1 = amrow[m2 + 1];
            const float wd0 = wdsr[m2],      wd1 = wdsr[m2 + 1];
            #pragma unroll
            for (int rr = 0; rr < 8; ++rr) {
                const int row = rr * 8 + w;
                const int jg  = j0 + row;
                const float2 bv = *(const float2*)&B[(size_t)jg * NH + m2];
                const float d = distrow[jg];
                const float v0 = fmaxf(am0 + bv.x + d * wd0, 0.0f);
                const float v1 = fmaxf(am1 + bv.y + d * wd1, 0.0f);
                const unsigned p = (unsigned)(unsigned short)f2bf(v0) |
                                   ((unsigned)(unsigned short)f2bf(v1) << 16);
                *(unsigned*)&h1s[row * HSTR + m2] = p;
            }
        }
        __syncthreads();

        // ---- GEMM1: h2 = relu(h1 @ W2^T + b2) ----
        {
            f32x4 acc[2][2] = {{{0,0,0,0},{0,0,0,0}},{{0,0,0,0},{0,0,0,0}}};
            #pragma unroll
            for (int jt = 0; jt < 2; ++jt) {
                const short* arow = &h1s[(g * 32 + jt * 16 + c) * HSTR + q * 8];
                #pragma unroll
                for (int kb = 0; kb < 4; ++kb) {
                    bf16x8 a = *(const bf16x8*)(arow + kb * 32);
                    acc[jt][0] = __builtin_amdgcn_mfma_f32_16x16x32_bf16(a, w2f[0][kb], acc[jt][0], 0, 0, 0);
                    acc[jt][1] = __builtin_amdgcn_mfma_f32_16x16x32_bf16(a, w2f[1][kb], acc[jt][1], 0, 0, 0);
                }
            }
            #pragma unroll
            for (int jt = 0; jt < 2; ++jt)
                #pragma unroll
                for (int r = 0; r < 4; ++r) {
                    const int row = g * 32 + jt * 16 + q * 4 + r;
                    h2s[row * HSTR + n0] = f2bf(fmaxf(acc[jt][0][r] + b2n0, 0.0f));
                    h2s[row * HSTR + n1] = f2bf(fmaxf(acc[jt][1][r] + b2n1, 0.0f));
                }
        }
        __syncthreads();

        // ---- GEMM2: diag-masked column sum of h2 @ W3^T + b3 ----
        {
            f32x4 acc[2][2] = {{{0,0,0,0},{0,0,0,0}},{{0,0,0,0},{0,0,0,0}}};
            #pragma unroll
            for (int jt = 0; jt < 2; ++jt) {
                const short* arow = &h2s[(g * 32 + jt * 16 + c) * HSTR + q * 8];
                #pragma unroll
                for (int kb = 0; kb < 4; ++kb) {
                    bf16x8 a = *(const bf16x8*)(arow + kb * 32);
                    acc[jt][0] = __builtin_amdgcn_mfma_f32_16x16x32_bf16(a, w3f[0][kb], acc[jt][0], 0, 0, 0);
                    acc[jt][1] = __builtin_amdgcn_mfma_f32_16x16x32_bf16(a, w3f[1][kb], acc[jt][1], 0, 0, 0);
                }
            }
            #pragma unroll
            for (int jt = 0; jt < 2; ++jt)
                #pragma unroll
                for (int r = 0; r < 4; ++r) {
                    const int jg = j0 + g * 32 + jt * 16 + q * 4 + r;
                    if (jg != i) {
                        psum0 += acc[jt][0][r] + b3n0;
                        psum1 += acc[jt][1][r] + b3n1;
                    }
                }
        }
    }

    // ---- msum: reduce over quads, then over the 2 row-groups via LDS ----
    psum0 += __shfl_xor(psum0, 16, 64);
    psum0 += __shfl_xor(psum0, 32, 64);
    psum1 += __shfl_xor(psum1, 16, 64);
    psum1 += __shfl_xor(psum1, 32, 64);
    if (lane < 16) {
        atomicAdd(&msum_s[n0], psum0);
        atomicAdd(&msum_s[n1], psum1);
    }
    __syncthreads();
    if (t < NH) xs2[NH + t] = msum_s[t];
    __syncthreads();

    // ---- tail: update MLP, coalesced GEMV (wave = row, lanes split k) ----
    // L1: K=256
    {
        const float4 xv = *(const float4*)&xs2[lane * 4];
        #pragma unroll 4
        for (int rr = 0; rr < 16; ++rr) {
            const int n = w * 16 + rr;
            const float4 wv = *(const float4*)&uW1[(size_t)n * 256 + lane * 4];
            float p = wv.x * xv.x + wv.y * xv.y + wv.z * xv.z + wv.w * xv.w;
            #pragma unroll
            for (int s2 = 1; s2 < 64; s2 <<= 1) p += __shfl_xor(p, s2, 64);
            if (lane == rr) hx[n] = fmaxf(ub1[n] + p, 0.f);
        }
    }
    __syncthreads();
    // L2: K=128
    {
        const float2 xv = *(const float2*)&hx[lane * 2];
        #pragma unroll 4
        for (int rr = 0; rr < 16; ++rr) {
            const int n = w * 16 + rr;
            const float2 wv = *(const float2*)&uW2[(size_t)n * NH + lane * 2];
            float p = wv.x * xv.x + wv.y * xv.y;
            #pragma unroll
            for (int s2 = 1; s2 < 64; s2 <<= 1) p += __shfl_xor(p, s2, 64);
            if (lane == rr) hy[n] = fmaxf(ub2[n] + p, 0.f);
        }
    }
    __syncthreads();
    // L3: K=128, no relu -> zout + hz
    {
        const float2 xv = *(const float2*)&hy[lane * 2];
        #pragma unroll 4
        for (int rr = 0; rr < 16; ++rr) {
            const int n = w * 16 + rr;
            const float2 wv = *(const float2*)&uW3[(size_t)n * NH + lane * 2];
            float p = wv.x * xv.x + wv.y * xv.y;
            #pragma unroll
            for (int s2 = 1; s2 < 64; s2 <<= 1) p += __shfl_xor(p, s2, 64);
            if (lane == rr) {
                const float v = ub3[n] + p;
                zout[(size_t)i * NH + n] = v;
                hz[n] = v;
            }
        }
    }
    if (!do_ab) return;
    __syncthreads();
    // ab: A = z@Wi^T, B = z@Wj^T (K=128, row stride 257 -> scalar loads)
    {
        const float2 zv = *(const float2*)&hz[lane * 2];
        #pragma unroll 2
        for (int rr = 0; rr < 16; ++rr) {
            const int n = w * 16 + rr;
            const float* pr = msgW1n + (size_t)n * 257 + lane * 2;
            float pa = pr[0] * zv.x + pr[1] * zv.y;
            float pb = pr[NH] * zv.x + pr[NH + 1] * zv.y;
            #pragma unroll
            for (int s2 = 1; s2 < 64; s2 <<= 1) {
                pa += __shfl_xor(pa, s2, 64);
                pb += __shfl_xor(pb, s2, 64);
            }
            if (lane == rr) {
                An[(size_t)i * NH + n] = pa;
                Bn[(size_t)i * NH + n] = pb;
            }
        }
    }
}

// ---------------------------------------------------------------- host ------
extern "C" void kernel_launch(void* const* d_in, const int* in_sizes, int n_in,
                              void* d_out, int out_size, void* d_ws, size_t ws_size,
                              hipStream_t stream) {
    fp32p obs   = (fp32p)d_in[0];
    fp32p pos   = (fp32p)d_in[1];
    fp32p encW1 = (fp32p)d_in[2];  fp32p encb1 = (fp32p)d_in[3];
    fp32p encW2 = (fp32p)d_in[4];  fp32p encb2 = (fp32p)d_in[5];
    fp32p encW3 = (fp32p)d_in[6];  fp32p encb3 = (fp32p)d_in[7];
    fp32p msgW1 = (fp32p)d_in[8];  fp32p msgb1 = (fp32p)d_in[9];
    fp32p msgW2 = (fp32p)d_in[10]; fp32p msgb2 = (fp32p)d_in[11];
    fp32p msgW3 = (fp32p)d_in[12]; fp32p msgb3 = (fp32p)d_in[13];
    fp32p updW1 = (fp32p)d_in[14]; fp32p updb1 = (fp32p)d_in[15];
    fp32p updW2 = (fp32p)d_in[16]; fp32p updb2 = (fp32p)d_in[17];
    fp32p updW3 = (fp32p)d_in[18]; fp32p updb3 = (fp32p)d_in[19];

    // workspace (fp32): zA | zB | A0 | B0 | A1 | B1  (1.5 MB)
    float* ws = (float*)d_ws;
    float* zA = ws;
    float* zB = zA + NA * NH;
    float* A0 = zB + NA * NH;
    float* B0 = A0 + NA * NH;
    float* A1 = B0 + NA * NH;
    float* B1 = A1 + NA * NH;

    enc_ab_kernel<<<32, 512, 0, stream>>>(obs, encW1, encb1, encW2, encb2,
                                          encW3, encb3, msgW1, zA, A0, B0);

    float* zin = zA;  float* zout = zB;
    float* Ac = A0;   float* Bc = B0;
    float* An = A1;   float* Bn = B1;
    for (int l = 0; l < 3; ++l) {
        const int do_ab = (l < 2);
        float* dst = (l == 2) ? (float*)d_out : zout;
        msg_upd_kernel<<<NA, 512, 0, stream>>>(Ac, Bc, pos, zin,
            msgW1 + (size_t)l * 128 * 257, msgb1 + l * 128,
            msgW2 + (size_t)l * 128 * 128, msgb2 + l * 128,
            msgW3 + (size_t)l * 128 * 128, msgb3 + l * 128,
            updW1 + (size_t)l * 256 * 128, updb1 + l * 128,
            updW2 + (size_t)l * 128 * 128, updb2 + l * 128,
            updW3 + (size_t)l * 128 * 128, updb3 + l * 128,
            msgW1 + (size_t)(l + 1 < 3 ? l + 1 : 0) * 128 * 257, do_ab,
            dst, An, Bn);
        float* tmp;
        tmp = zin; zin = zout; zout = tmp;
        tmp = Ac; Ac = An; An = tmp;
        tmp = Bc; Bc = Bn; Bn = tmp;
    }
}

// Round 7
// 310.047 us; speedup vs baseline: 1.0433x; 1.0433x over previous
//
#include <hip/hip_runtime.h>

// Problem constants (from reference): N=512, OBS=32, H=128, M=128, L=3
#define NA 512
#define NOBS 32
#define NH 128

typedef const float* fp32p;
typedef __attribute__((ext_vector_type(8))) short bf16x8;
typedef __attribute__((ext_vector_type(4))) float f32x4;

// fp32 -> bf16 (RNE) bit pattern
__device__ __forceinline__ short f2bf(float f) {
    union { float f; unsigned u; } v; v.f = f;
    unsigned r = v.u + 0x7fffu + ((v.u >> 16) & 1u);
    return (short)(r >> 16);
}

__device__ __forceinline__ bf16x8 wfrag_f4(const float* p) {  // 16B-aligned
    float4 u = *(const float4*)p;
    float4 v = *(const float4*)(p + 4);
    bf16x8 f;
    f[0] = f2bf(u.x); f[1] = f2bf(u.y); f[2] = f2bf(u.z); f[3] = f2bf(u.w);
    f[4] = f2bf(v.x); f[5] = f2bf(v.y); f[6] = f2bf(v.z); f[7] = f2bf(v.w);
    return f;
}
__device__ __forceinline__ bf16x8 wfrag_s(const float* p) {   // unaligned ok
    bf16x8 f;
    #pragma unroll
    for (int j = 0; j < 8; ++j) f[j] = f2bf(p[j]);
    return f;
}

#define HSTR 136   // LDS row stride (shorts) for 128-wide bf16 tiles
#define XSTR 40    // for 32-wide obs tile

// ------------------------------------------------ encoder + ab(layer0) -----
// grid 32 x 512; all weight fragments loaded before the first barrier so the
// 5-phase MFMA chain overlaps its global loads.
__global__ __launch_bounds__(512) void enc_ab_kernel(
    fp32p obs, fp32p W1, fp32p b1, fp32p W2, fp32p b2, fp32p W3, fp32p b3,
    fp32p msgW1, float* __restrict__ z, float* __restrict__ A, float* __restrict__ B) {
    const int a0 = blockIdx.x * 16;
    const int t = threadIdx.x;
    const int lane = t & 63, w = t >> 6, q = lane >> 4, c = lane & 15;
    const int ncol = w * 16 + c;

    __shared__ short xs[16 * XSTR];
    __shared__ short h1s[16 * HSTR];
    __shared__ short h2s[16 * HSTR];

    // hoisted weight fragments (independent of LDS)
    bf16x8 wf = wfrag_f4(W1 + (size_t)ncol * NOBS + q * 8);
    bf16x8 w2f[4], w3f[4], wif[4], wjf[4];
    #pragma unroll
    for (int kb = 0; kb < 4; ++kb) {
        w2f[kb] = wfrag_f4(W2 + (size_t)ncol * NH + kb * 32 + q * 8);
        w3f[kb] = wfrag_f4(W3 + (size_t)ncol * NH + kb * 32 + q * 8);
        const float* pr = msgW1 + (size_t)ncol * 257 + kb * 32 + q * 8;
        wif[kb] = wfrag_s(pr);
        wjf[kb] = wfrag_s(pr + NH);
    }
    const float bias1 = b1[ncol], bias2 = b2[ncol], bias3 = b3[ncol];

    {   // 512 threads, 512 elements
        const int r = t >> 5, k = t & 31;
        xs[r * XSTR + k] = f2bf(obs[(size_t)(a0 + r) * NOBS + k]);
    }
    __syncthreads();
    // L1 (K=32)
    {
        f32x4 acc = {0.f, 0.f, 0.f, 0.f};
        bf16x8 a = *(const bf16x8*)&xs[c * XSTR + q * 8];
        acc = __builtin_amdgcn_mfma_f32_16x16x32_bf16(a, wf, acc, 0, 0, 0);
        #pragma unroll
        for (int r = 0; r < 4; ++r)
            h1s[(q * 4 + r) * HSTR + ncol] = f2bf(fmaxf(acc[r] + bias1, 0.f));
    }
    __syncthreads();
    // L2 (K=128)
    {
        f32x4 acc = {0.f, 0.f, 0.f, 0.f};
        #pragma unroll
        for (int kb = 0; kb < 4; ++kb) {
            bf16x8 a = *(const bf16x8*)&h1s[c * HSTR + kb * 32 + q * 8];
            acc = __builtin_amdgcn_mfma_f32_16x16x32_bf16(a, w2f[kb], acc, 0, 0, 0);
        }
        #pragma unroll
        for (int r = 0; r < 4; ++r)
            h2s[(q * 4 + r) * HSTR + ncol] = f2bf(fmaxf(acc[r] + bias2, 0.f));
    }
    __syncthreads();
    // L3 (K=128, no relu) -> z fp32 + bf16 back into h1s
    {
        f32x4 acc = {0.f, 0.f, 0.f, 0.f};
        #pragma unroll
        for (int kb = 0; kb < 4; ++kb) {
            bf16x8 a = *(const bf16x8*)&h2s[c * HSTR + kb * 32 + q * 8];
            acc = __builtin_amdgcn_mfma_f32_16x16x32_bf16(a, w3f[kb], acc, 0, 0, 0);
        }
        #pragma unroll
        for (int r = 0; r < 4; ++r) {
            const int row = q * 4 + r;
            const float v = acc[r] + bias3;
            z[(size_t)(a0 + row) * NH + ncol] = v;
            h1s[row * HSTR + ncol] = f2bf(v);
        }
    }
    __syncthreads();
    // ab for msg layer 0
    {
        f32x4 accA = {0.f, 0.f, 0.f, 0.f};
        f32x4 accB = {0.f, 0.f, 0.f, 0.f};
        #pragma unroll
        for (int kb = 0; kb < 4; ++kb) {
            bf16x8 a = *(const bf16x8*)&h1s[c * HSTR + kb * 32 + q * 8];
            accA = __builtin_amdgcn_mfma_f32_16x16x32_bf16(a, wif[kb], accA, 0, 0, 0);
            accB = __builtin_amdgcn_mfma_f32_16x16x32_bf16(a, wjf[kb], accB, 0, 0, 0);
        }
        #pragma unroll
        for (int r = 0; r < 4; ++r) {
            const int row = q * 4 + r;
            A[(size_t)(a0 + row) * NH + ncol] = accA[r];
            B[(size_t)(a0 + row) * NH + ncol] = accB[r];
        }
    }
}

// -------------------------------------- fused message + update + next-ab ----
// One block per agent i; 8 waves. Msg GEMM structure = round 5 (1 n-tile per
// wave, 8 register frags = 32 VGPRs; round 6's 2-tile pairing spilled to
// scratch: WRITE_SIZE 768KB->17MB, regression). Tail = round 6's coalesced
// GEMV (wave = one output row, lanes split k, shuffle-reduce) which fixes
// round 5's 64-lines-per-instruction weight reads. NO restrictive
// launch_bounds: (512,4)'s 128-reg cap is what triggered the spills.
__global__ __launch_bounds__(512) void msg_upd_kernel(
    const float* __restrict__ A, const float* __restrict__ B,
    fp32p pos, const float* __restrict__ zin,
    fp32p W1l, fp32p b1, fp32p W2, fp32p b2, fp32p W3, fp32p b3,
    fp32p uW1, fp32p ub1, fp32p uW2, fp32p ub2, fp32p uW3, fp32p ub3,
    fp32p msgW1n, int do_ab,
    float* __restrict__ zout, float* __restrict__ An, float* __restrict__ Bn) {
    const int i = blockIdx.x;
    const int t = threadIdx.x;
    const int lane = t & 63;
    const int w = t >> 6;
    const int q = lane >> 4;
    const int c = lane & 15;
    const int ncol = w * 16 + c;

    __shared__ short h1s[64 * HSTR];   // 17408 B
    __shared__ short h2s[64 * HSTR];   // 17408 B
    __shared__ float distrow[NA];
    __shared__ float amrow[NH];        // A_i + b1 folded
    __shared__ float wdsr[NH];
    __shared__ float msum_s[NH];
    __shared__ float xs2[2 * NH];      // [z_i | msum_i]
    __shared__ float hx[NH], hy[NH], hz[NH];

    if (t < NH) {
        amrow[t] = A[i * NH + t] + b1[t];
        wdsr[t]  = W1l[t * 257 + 256];
        xs2[t] = zin[(size_t)i * NH + t];
    }
    {
        const float2 pi = *(const float2*)&pos[2 * i];
        const float2 pj = *(const float2*)&pos[2 * t];
        const float dx = pi.x - pj.x, dy = pi.y - pj.y;
        const float s = dx * dx + dy * dy;
        distrow[t] = (t == i) ? 0.0f : sqrtf(s);
    }

    // register-resident weight fragments (one 16-col n-tile per wave)
    bf16x8 w2f[4], w3f[4];
    {
        const float* w2r = W2 + (size_t)ncol * NH + q * 8;
        const float* w3r = W3 + (size_t)ncol * NH + q * 8;
        #pragma unroll
        for (int kb = 0; kb < 4; ++kb) {
            w2f[kb] = wfrag_f4(w2r + kb * 32);
            w3f[kb] = wfrag_f4(w3r + kb * 32);
        }
    }
    const float b2n = b2[ncol];
    const float b3n = b3[ncol];

    const int m2 = lane * 2;
    float psum = 0.0f;

    for (int c8 = 0; c8 < 8; ++c8) {
        const int j0 = c8 * 64;
        __syncthreads();

        // ---- build h1 chunk (64 x 128) as bf16 ----
        {
            const float am0 = amrow[m2],     am1 = amrow[m2 + 1];
            const float wd0 = wdsr[m2],      wd1 = wdsr[m2 + 1];
            #pragma unroll
            for (int rr = 0; rr < 8; ++rr) {
                const int row = rr * 8 + w;
                const int jg  = j0 + row;
                const float2 bv = *(const float2*)&B[(size_t)jg * NH + m2];
                const float d = distrow[jg];
                const float v0 = fmaxf(am0 + bv.x + d * wd0, 0.0f);
                const float v1 = fmaxf(am1 + bv.y + d * wd1, 0.0f);
                const unsigned p = (unsigned)(unsigned short)f2bf(v0) |
                                   ((unsigned)(unsigned short)f2bf(v1) << 16);
                *(unsigned*)&h1s[row * HSTR + m2] = p;
            }
        }
        __syncthreads();

        // ---- GEMM1: h2 = relu(h1 @ W2^T + b2) ----
        #pragma unroll
        for (int jt = 0; jt < 4; ++jt) {
            f32x4 acc = {0.f, 0.f, 0.f, 0.f};
            const short* arow = &h1s[(jt * 16 + c) * HSTR + q * 8];
            #pragma unroll
            for (int kb = 0; kb < 4; ++kb) {
                bf16x8 a = *(const bf16x8*)(arow + kb * 32);
                acc = __builtin_amdgcn_mfma_f32_16x16x32_bf16(a, w2f[kb], acc, 0, 0, 0);
            }
            #pragma unroll
            for (int r = 0; r < 4; ++r) {
                const int row = jt * 16 + q * 4 + r;
                h2s[row * HSTR + ncol] = f2bf(fmaxf(acc[r] + b2n, 0.0f));
            }
        }
        __syncthreads();

        // ---- GEMM2: diag-masked column sum of h2 @ W3^T + b3 ----
        #pragma unroll
        for (int jt = 0; jt < 4; ++jt) {
            f32x4 acc = {0.f, 0.f, 0.f, 0.f};
            const short* arow = &h2s[(jt * 16 + c) * HSTR + q * 8];
            #pragma unroll
            for (int kb = 0; kb < 4; ++kb) {
                bf16x8 a = *(const bf16x8*)(arow + kb * 32);
                acc = __builtin_amdgcn_mfma_f32_16x16x32_bf16(a, w3f[kb], acc, 0, 0, 0);
            }
            #pragma unroll
            for (int r = 0; r < 4; ++r) {
                const int jg = j0 + jt * 16 + q * 4 + r;
                if (jg != i) psum += acc[r] + b3n;
            }
        }
    }

    // ---- msum: reduce over quads (same ncol), single-owner store ----
    psum += __shfl_xor(psum, 16, 64);
    psum += __shfl_xor(psum, 32, 64);
    if (lane < 16) msum_s[ncol] = psum;
    __syncthreads();
    if (t < NH) xs2[NH + t] = msum_s[t];
    __syncthreads();

    // ---- tail: update MLP, coalesced GEMV (wave = row, lanes split k) ----
    // L1: K=256
    {
        const float4 xv = *(const float4*)&xs2[lane * 4];
        #pragma unroll 4
        for (int rr = 0; rr < 16; ++rr) {
            const int n = w * 16 + rr;
            const float4 wv = *(const float4*)&uW1[(size_t)n * 256 + lane * 4];
            float p = wv.x * xv.x + wv.y * xv.y + wv.z * xv.z + wv.w * xv.w;
            #pragma unroll
            for (int s2 = 1; s2 < 64; s2 <<= 1) p += __shfl_xor(p, s2, 64);
            if (lane == rr) hx[n] = fmaxf(ub1[n] + p, 0.f);
        }
    }
    __syncthreads();
    // L2: K=128
    {
        const float2 xv = *(const float2*)&hx[lane * 2];
        #pragma unroll 4
        for (int rr = 0; rr < 16; ++rr) {
            const int n = w * 16 + rr;
            const float2 wv = *(const float2*)&uW2[(size_t)n * NH + lane * 2];
            float p = wv.x * xv.x + wv.y * xv.y;
            #pragma unroll
            for (int s2 = 1; s2 < 64; s2 <<= 1) p += __shfl_xor(p, s2, 64);
            if (lane == rr) hy[n] = fmaxf(ub2[n] + p, 0.f);
        }
    }
    __syncthreads();
    // L3: K=128, no relu -> zout + hz
    {
        const float2 xv = *(const float2*)&hy[lane * 2];
        #pragma unroll 4
        for (int rr = 0; rr < 16; ++rr) {
            const int n = w * 16 + rr;
            const float2 wv = *(const float2*)&uW3[(size_t)n * NH + lane * 2];
            float p = wv.x * xv.x + wv.y * xv.y;
            #pragma unroll
            for (int s2 = 1; s2 < 64; s2 <<= 1) p += __shfl_xor(p, s2, 64);
            if (lane == rr) {
                const float v = ub3[n] + p;
                zout[(size_t)i * NH + n] = v;
                hz[n] = v;
            }
        }
    }
    if (!do_ab) return;
    __syncthreads();
    // ab: A = z@Wi^T, B = z@Wj^T (K=128, row stride 257 -> scalar loads)
    {
        const float2 zv = *(const float2*)&hz[lane * 2];
        #pragma unroll 2
        for (int rr = 0; rr < 16; ++rr) {
            const int n = w * 16 + rr;
            const float* pr = msgW1n + (size_t)n * 257 + lane * 2;
            float pa = pr[0] * zv.x + pr[1] * zv.y;
            float pb = pr[NH] * zv.x + pr[NH + 1] * zv.y;
            #pragma unroll
            for (int s2 = 1; s2 < 64; s2 <<= 1) {
                pa += __shfl_xor(pa, s2, 64);
                pb += __shfl_xor(pb, s2, 64);
            }
            if (lane == rr) {
                An[(size_t)i * NH + n] = pa;
                Bn[(size_t)i * NH + n] = pb;
            }
        }
    }
}

// ---------------------------------------------------------------- host ------
extern "C" void kernel_launch(void* const* d_in, const int* in_sizes, int n_in,
                              void* d_out, int out_size, void* d_ws, size_t ws_size,
                              hipStream_t stream) {
    fp32p obs   = (fp32p)d_in[0];
    fp32p pos   = (fp32p)d_in[1];
    fp32p encW1 = (fp32p)d_in[2];  fp32p encb1 = (fp32p)d_in[3];
    fp32p encW2 = (fp32p)d_in[4];  fp32p encb2 = (fp32p)d_in[5];
    fp32p encW3 = (fp32p)d_in[6];  fp32p encb3 = (fp32p)d_in[7];
    fp32p msgW1 = (fp32p)d_in[8];  fp32p msgb1 = (fp32p)d_in[9];
    fp32p msgW2 = (fp32p)d_in[10]; fp32p msgb2 = (fp32p)d_in[11];
    fp32p msgW3 = (fp32p)d_in[12]; fp32p msgb3 = (fp32p)d_in[13];
    fp32p updW1 = (fp32p)d_in[14]; fp32p updb1 = (fp32p)d_in[15];
    fp32p updW2 = (fp32p)d_in[16]; fp32p updb2 = (fp32p)d_in[17];
    fp32p updW3 = (fp32p)d_in[18]; fp32p updb3 = (fp32p)d_in[19];

    // workspace (fp32): zA | zB | A0 | B0 | A1 | B1  (1.5 MB)
    float* ws = (float*)d_ws;
    float* zA = ws;
    float* zB = zA + NA * NH;
    float* A0 = zB + NA * NH;
    float* B0 = A0 + NA * NH;
    float* A1 = B0 + NA * NH;
    float* B1 = A1 + NA * NH;

    enc_ab_kernel<<<32, 512, 0, stream>>>(obs, encW1, encb1, encW2, encb2,
                                          encW3, encb3, msgW1, zA, A0, B0);

    float* zin = zA;  float* zout = zB;
    float* Ac = A0;   float* Bc = B0;
    float* An = A1;   float* Bn = B1;
    for (int l = 0; l < 3; ++l) {
        const int do_ab = (l < 2);
        float* dst = (l == 2) ? (float*)d_out : zout;
        msg_upd_kernel<<<NA, 512, 0, stream>>>(Ac, Bc, pos, zin,
            msgW1 + (size_t)l * 128 * 257, msgb1 + l * 128,
            msgW2 + (size_t)l * 128 * 128, msgb2 + l * 128,
            msgW3 + (size_t)l * 128 * 128, msgb3 + l * 128,
            updW1 + (size_t)l * 256 * 128, updb1 + l * 128,
            updW2 + (size_t)l * 128 * 128, updb2 + l * 128,
            updW3 + (size_t)l * 128 * 128, updb3 + l * 128,
            msgW1 + (size_t)(l + 1 < 3 ? l + 1 : 0) * 128 * 257, do_ab,
            dst, An, Bn);
        float* tmp;
        tmp = zin; zin = zout; zout = tmp;
        tmp = Ac; Ac = An; An = tmp;
        tmp = Bc; Bc = Bn; Bn = tmp;
    }
}

// Round 8
// 239.488 us; speedup vs baseline: 1.3506x; 1.2946x over previous
//
#include <hip/hip_runtime.h>

// Problem constants (from reference): N=512, OBS=32, H=128, M=128, L=3
#define NA 512
#define NOBS 32
#define NH 128

typedef const float* fp32p;
typedef __attribute__((ext_vector_type(8))) short bf16x8;
typedef __attribute__((ext_vector_type(4))) float f32x4;

// fp32 -> bf16 (RNE) bit pattern
__device__ __forceinline__ short f2bf(float f) {
    union { float f; unsigned u; } v; v.f = f;
    unsigned r = v.u + 0x7fffu + ((v.u >> 16) & 1u);
    return (short)(r >> 16);
}

__device__ __forceinline__ bf16x8 wfrag_f4(const float* p) {  // 16B-aligned
    float4 u = *(const float4*)p;
    float4 v = *(const float4*)(p + 4);
    bf16x8 f;
    f[0] = f2bf(u.x); f[1] = f2bf(u.y); f[2] = f2bf(u.z); f[3] = f2bf(u.w);
    f[4] = f2bf(v.x); f[5] = f2bf(v.y); f[6] = f2bf(v.z); f[7] = f2bf(v.w);
    return f;
}

#define HSTR 136   // LDS row stride (shorts) for 128-wide bf16 tiles

// ------------------------------------------------------------- encoder ------
// Round-2 proven-cheap style: grid 512 x 128, GEMV per agent, weights L2-hot.
__global__ __launch_bounds__(128) void encoder_kernel(
    fp32p obs, fp32p W1, fp32p b1, fp32p W2, fp32p b2, fp32p W3, fp32p b3,
    float* __restrict__ z) {
    __shared__ float xs[NOBS];
    __shared__ float h1s[NH];
    __shared__ float h2s[NH];
    const int i = blockIdx.x, t = threadIdx.x;
    if (t < NOBS) xs[t] = obs[i * NOBS + t];
    __syncthreads();
    float a = b1[t];
    for (int k = 0; k < NOBS; ++k) a += xs[k] * W1[t * NOBS + k];
    h1s[t] = fmaxf(a, 0.0f);
    __syncthreads();
    a = b2[t];
    for (int k = 0; k < NH; ++k) a += h1s[k] * W2[t * NH + k];
    h2s[t] = fmaxf(a, 0.0f);
    __syncthreads();
    a = b3[t];
    for (int k = 0; k < NH; ++k) a += h2s[k] * W3[t * NH + k];
    z[i * NH + t] = a;
}

// ------------------------------------------------- A = z@Wi.T, B = z@Wj.T ---
__global__ __launch_bounds__(128) void ab_kernel(
    const float* __restrict__ z, fp32p W1l, float* __restrict__ A, float* __restrict__ B) {
    __shared__ float zs[NH];
    const int i = blockIdx.x, m = threadIdx.x;
    zs[m] = z[i * NH + m];
    __syncthreads();
    const float* wr = W1l + m * 257;
    float a = 0.0f, b = 0.0f;
    for (int k = 0; k < NH; ++k) {
        float zk = zs[k];
        a += zk * wr[k];
        b += zk * wr[NH + k];
    }
    A[i * NH + m] = a;
    B[i * NH + m] = b;
}

// -------------------------------------- fused message + update + next-ab ----
// One block per agent i; 8 waves. Msg GEMM = round 5/7 proven structure
// (1 n-tile/wave, 8 register frags, no restrictive launch_bounds).
// Tail = LDS-partials GEMV (round-5 style, measured 22us) with 4-lanes-per-
// row indexing (n=t>>2, ks=t&3): 16 cache lines per VMEM instr instead of
// 64, no shuffle chains (round 7's 6-deep shfl chains were 42us).
__global__ __launch_bounds__(512) void msg_upd_kernel(
    const float* __restrict__ A, const float* __restrict__ B,
    fp32p pos, const float* __restrict__ zin,
    fp32p W1l, fp32p b1, fp32p W2, fp32p b2, fp32p W3, fp32p b3,
    fp32p uW1, fp32p ub1, fp32p uW2, fp32p ub2, fp32p uW3, fp32p ub3,
    fp32p msgW1n, int do_ab,
    float* __restrict__ zout, float* __restrict__ An, float* __restrict__ Bn) {
    const int i = blockIdx.x;
    const int t = threadIdx.x;
    const int lane = t & 63;
    const int w = t >> 6;
    const int q = lane >> 4;
    const int c = lane & 15;
    const int ncol = w * 16 + c;

    __shared__ short h1s[64 * HSTR];   // 17408 B
    __shared__ short h2s[64 * HSTR];   // 17408 B
    __shared__ float distrow[NA];
    __shared__ float amrow[NH];        // A_i + b1 folded
    __shared__ float wdsr[NH];
    __shared__ float xs2[2 * NH];      // [z_i | msum_i]
    __shared__ float part[4 * NH];
    __shared__ float part2[4 * NH];
    __shared__ float hx[NH], hy[NH], hz[NH];

    if (t < NH) {
        amrow[t] = A[i * NH + t] + b1[t];
        wdsr[t]  = W1l[t * 257 + 256];
        xs2[t] = zin[(size_t)i * NH + t];
    }
    {
        const float2 pi = *(const float2*)&pos[2 * i];
        const float2 pj = *(const float2*)&pos[2 * t];
        const float dx = pi.x - pj.x, dy = pi.y - pj.y;
        const float s = dx * dx + dy * dy;
        distrow[t] = (t == i) ? 0.0f : sqrtf(s);
    }

    // register-resident weight fragments (one 16-col n-tile per wave)
    bf16x8 w2f[4], w3f[4];
    {
        const float* w2r = W2 + (size_t)ncol * NH + q * 8;
        const float* w3r = W3 + (size_t)ncol * NH + q * 8;
        #pragma unroll
        for (int kb = 0; kb < 4; ++kb) {
            w2f[kb] = wfrag_f4(w2r + kb * 32);
            w3f[kb] = wfrag_f4(w3r + kb * 32);
        }
    }
    const float b2n = b2[ncol];
    const float b3n = b3[ncol];

    const int m2 = lane * 2;
    float psum = 0.0f;

    for (int c8 = 0; c8 < 8; ++c8) {
        const int j0 = c8 * 64;
        __syncthreads();

        // ---- build h1 chunk (64 x 128) as bf16 ----
        {
            const float am0 = amrow[m2],     am1 = amrow[m2 + 1];
            const float wd0 = wdsr[m2],      wd1 = wdsr[m2 + 1];
            #pragma unroll
            for (int rr = 0; rr < 8; ++rr) {
                const int row = rr * 8 + w;
                const int jg  = j0 + row;
                const float2 bv = *(const float2*)&B[(size_t)jg * NH + m2];
                const float d = distrow[jg];
                const float v0 = fmaxf(am0 + bv.x + d * wd0, 0.0f);
                const float v1 = fmaxf(am1 + bv.y + d * wd1, 0.0f);
                const unsigned p = (unsigned)(unsigned short)f2bf(v0) |
                                   ((unsigned)(unsigned short)f2bf(v1) << 16);
                *(unsigned*)&h1s[row * HSTR + m2] = p;
            }
        }
        __syncthreads();

        // ---- GEMM1: h2 = relu(h1 @ W2^T + b2) ----
        #pragma unroll
        for (int jt = 0; jt < 4; ++jt) {
            f32x4 acc = {0.f, 0.f, 0.f, 0.f};
            const short* arow = &h1s[(jt * 16 + c) * HSTR + q * 8];
            #pragma unroll
            for (int kb = 0; kb < 4; ++kb) {
                bf16x8 a = *(const bf16x8*)(arow + kb * 32);
                acc = __builtin_amdgcn_mfma_f32_16x16x32_bf16(a, w2f[kb], acc, 0, 0, 0);
            }
            #pragma unroll
            for (int r = 0; r < 4; ++r) {
                const int row = jt * 16 + q * 4 + r;
                h2s[row * HSTR + ncol] = f2bf(fmaxf(acc[r] + b2n, 0.0f));
            }
        }
        __syncthreads();

        // ---- GEMM2: diag-masked column sum of h2 @ W3^T + b3 ----
        #pragma unroll
        for (int jt = 0; jt < 4; ++jt) {
            f32x4 acc = {0.f, 0.f, 0.f, 0.f};
            const short* arow = &h2s[(jt * 16 + c) * HSTR + q * 8];
            #pragma unroll
            for (int kb = 0; kb < 4; ++kb) {
                bf16x8 a = *(const bf16x8*)(arow + kb * 32);
                acc = __builtin_amdgcn_mfma_f32_16x16x32_bf16(a, w3f[kb], acc, 0, 0, 0);
            }
            #pragma unroll
            for (int r = 0; r < 4; ++r) {
                const int jg = j0 + jt * 16 + q * 4 + r;
                if (jg != i) psum += acc[r] + b3n;
            }
        }
    }

    // ---- msum: reduce over quads (same ncol), write straight into xs2 ----
    psum += __shfl_xor(psum, 16, 64);
    psum += __shfl_xor(psum, 32, 64);
    if (lane < 16) xs2[NH + ncol] = psum;
    __syncthreads();

    // ---- tail: update MLP (fp32 GEMV, 4 lanes per output row) ----
    const int nn = t >> 2;   // output row 0..127
    const int ks = t & 3;    // k-segment
    // L1: K=256
    {
        const float* wr = uW1 + (size_t)nn * 256 + ks * 4;
        float p = 0.f;
        #pragma unroll
        for (int it = 0; it < 16; ++it) {
            const float4 wv = *(const float4*)(wr + it * 16);
            const float4 xv = *(const float4*)&xs2[it * 16 + ks * 4];
            p += wv.x * xv.x + wv.y * xv.y + wv.z * xv.z + wv.w * xv.w;
        }
        part[ks * NH + nn] = p;
    }
    __syncthreads();
    if (t < NH)
        hx[t] = fmaxf(ub1[t] + part[t] + part[NH + t] + part[2 * NH + t] + part[3 * NH + t], 0.f);
    __syncthreads();
    // L2: K=128
    {
        const float* wr = uW2 + (size_t)nn * NH + ks * 4;
        float p = 0.f;
        #pragma unroll
        for (int it = 0; it < 8; ++it) {
            const float4 wv = *(const float4*)(wr + it * 16);
            const float4 xv = *(const float4*)&hx[it * 16 + ks * 4];
            p += wv.x * xv.x + wv.y * xv.y + wv.z * xv.z + wv.w * xv.w;
        }
        part[ks * NH + nn] = p;
    }
    __syncthreads();
    if (t < NH)
        hy[t] = fmaxf(ub2[t] + part[t] + part[NH + t] + part[2 * NH + t] + part[3 * NH + t], 0.f);
    __syncthreads();
    // L3: K=128, no relu -> zout + hz
    {
        const float* wr = uW3 + (size_t)nn * NH + ks * 4;
        float p = 0.f;
        #pragma unroll
        for (int it = 0; it < 8; ++it) {
            const float4 wv = *(const float4*)(wr + it * 16);
            const float4 xv = *(const float4*)&hy[it * 16 + ks * 4];
            p += wv.x * xv.x + wv.y * xv.y + wv.z * xv.z + wv.w * xv.w;
        }
        part[ks * NH + nn] = p;
    }
    __syncthreads();
    if (t < NH) {
        const float v = ub3[t] + part[t] + part[NH + t] + part[2 * NH + t] + part[3 * NH + t];
        zout[(size_t)i * NH + t] = v;
        hz[t] = v;
    }
    if (!do_ab) return;
    __syncthreads();
    // ab: A = z@Wi^T, B = z@Wj^T (K=128, row stride 257 -> dword-safe loads)
    {
        const float* pr = msgW1n + (size_t)nn * 257;
        float pa = 0.f, pb = 0.f;
        #pragma unroll
        for (int it = 0; it < 8; ++it) {
            #pragma unroll
            for (int j = 0; j < 4; ++j) {
                const int k = it * 16 + ks * 4 + j;
                const float x = hz[k];
                pa += x * pr[k];
                pb += x * pr[NH + k];
            }
        }
        part[ks * NH + nn] = pa;
        part2[ks * NH + nn] = pb;
    }
    __syncthreads();
    if (t < NH) {
        An[(size_t)i * NH + t] = part[t] + part[NH + t] + part[2 * NH + t] + part[3 * NH + t];
        Bn[(size_t)i * NH + t] = part2[t] + part2[NH + t] + part2[2 * NH + t] + part2[3 * NH + t];
    }
}

// ---------------------------------------------------------------- host ------
extern "C" void kernel_launch(void* const* d_in, const int* in_sizes, int n_in,
                              void* d_out, int out_size, void* d_ws, size_t ws_size,
                              hipStream_t stream) {
    fp32p obs   = (fp32p)d_in[0];
    fp32p pos   = (fp32p)d_in[1];
    fp32p encW1 = (fp32p)d_in[2];  fp32p encb1 = (fp32p)d_in[3];
    fp32p encW2 = (fp32p)d_in[4];  fp32p encb2 = (fp32p)d_in[5];
    fp32p encW3 = (fp32p)d_in[6];  fp32p encb3 = (fp32p)d_in[7];
    fp32p msgW1 = (fp32p)d_in[8];  fp32p msgb1 = (fp32p)d_in[9];
    fp32p msgW2 = (fp32p)d_in[10]; fp32p msgb2 = (fp32p)d_in[11];
    fp32p msgW3 = (fp32p)d_in[12]; fp32p msgb3 = (fp32p)d_in[13];
    fp32p updW1 = (fp32p)d_in[14]; fp32p updb1 = (fp32p)d_in[15];
    fp32p updW2 = (fp32p)d_in[16]; fp32p updb2 = (fp32p)d_in[17];
    fp32p updW3 = (fp32p)d_in[18]; fp32p updb3 = (fp32p)d_in[19];

    // workspace (fp32): zA | zB | A0 | B0 | A1 | B1  (1.5 MB)
    float* ws = (float*)d_ws;
    float* zA = ws;
    float* zB = zA + NA * NH;
    float* A0 = zB + NA * NH;
    float* B0 = A0 + NA * NH;
    float* A1 = B0 + NA * NH;
    float* B1 = A1 + NA * NH;

    encoder_kernel<<<NA, 128, 0, stream>>>(obs, encW1, encb1, encW2, encb2,
                                           encW3, encb3, zA);
    ab_kernel<<<NA, 128, 0, stream>>>(zA, msgW1, A0, B0);

    float* zin = zA;  float* zout = zB;
    float* Ac = A0;   float* Bc = B0;
    float* An = A1;   float* Bn = B1;
    for (int l = 0; l < 3; ++l) {
        const int do_ab = (l < 2);
        float* dst = (l == 2) ? (float*)d_out : zout;
        msg_upd_kernel<<<NA, 512, 0, stream>>>(Ac, Bc, pos, zin,
            msgW1 + (size_t)l * 128 * 257, msgb1 + l * 128,
            msgW2 + (size_t)l * 128 * 128, msgb2 + l * 128,
            msgW3 + (size_t)l * 128 * 128, msgb3 + l * 128,
            updW1 + (size_t)l * 256 * 128, updb1 + l * 128,
            updW2 + (size_t)l * 128 * 128, updb2 + l * 128,
            updW3 + (size_t)l * 128 * 128, updb3 + l * 128,
            msgW1 + (size_t)(l + 1 < 3 ? l + 1 : 0) * 128 * 257, do_ab,
            dst, An, Bn);
        float* tmp;
        tmp = zin; zin = zout; zout = tmp;
        tmp = Ac; Ac = An; An = tmp;
        tmp = Bc; Bc = Bn; Bn = tmp;
    }
}